// Round 9
// baseline (89.659 us; speedup 1.0000x reference)
//
#include <hip/hip_runtime.h>

#define NQ 10
#define NL 3

typedef float    v2f __attribute__((ext_vector_type(2)));
typedef unsigned u2v __attribute__((ext_vector_type(2)));

#if defined(__has_builtin)
#if __has_builtin(__builtin_amdgcn_permlane16_swap) && __has_builtin(__builtin_amdgcn_permlane32_swap)
#define QNN_PERML 1
#endif
#endif

__device__ __forceinline__ int   f2i(float v) { union { float f; int i; } u; u.f = v; return u.i; }
__device__ __forceinline__ float i2f(int v)   { union { int i; float f; } u; u.i = v; return u.f; }

__device__ __forceinline__ v2f cmul(v2f a, v2f b) {
    return (v2f){ fmaf(a.x, b.x, -a.y * b.y), fmaf(a.x, b.y, a.y * b.x) };
}

template<int C> __device__ __forceinline__ int dppm(int v) {
    return __builtin_amdgcn_mov_dpp(v, C, 0xF, 0xF, false);
}

// ---- xor-16 / xor-32 lane exchange on the VALU pipe.
// v_permlane16_swap_b32 (vdst,vsrc): vdst.row[2r+1] <-> vsrc.row[2r].
// With vdst=vsrc=v: d has partner (lane^16) in ODD rows, s in EVEN rows.
__device__ __forceinline__ int x16(int v, int lane) {
#ifdef QNN_PERML
    u2v r = __builtin_amdgcn_permlane16_swap(v, v, false, false);
    return (lane & 16) ? (int)r.x : (int)r.y;
#else
    return __builtin_amdgcn_ds_swizzle(v, (16 << 10) | 0x1F);
#endif
}
// v_permlane32_swap_b32: vdst.rows[2,3] <-> vsrc.rows[0,1].
__device__ __forceinline__ int x32(int v, int lane) {
#ifdef QNN_PERML
    u2v r = __builtin_amdgcn_permlane32_swap(v, v, false, false);
    return (lane & 32) ? (int)r.x : (int)r.y;
#else
    return __builtin_amdgcn_ds_bpermute((lane ^ 32) << 2, v);
#endif
}

// xor exchange by mask LM, all-VALU. DPP atoms: 1(177) 2(78) 3(27) 7(321)
// 15(320); masks compose by XOR. Cross-row via permlane swaps.
template<int LM>
__device__ __forceinline__ int xli(int x, int lane) {
    if constexpr (LM == 0)       return x;
    else if constexpr (LM == 1)  return dppm<177>(x);
    else if constexpr (LM == 2)  return dppm<78>(x);
    else if constexpr (LM == 3)  return dppm<27>(x);
    else if constexpr (LM == 4)  return dppm<321>(dppm<27>(x));
    else if constexpr (LM == 5)  return dppm<321>(dppm<78>(x));
    else if constexpr (LM == 6)  return dppm<321>(dppm<177>(x));
    else if constexpr (LM == 7)  return dppm<321>(x);
    else if constexpr (LM == 8)  return dppm<320>(dppm<321>(x));
    else if constexpr (LM == 10) return dppm<320>(dppm<321>(dppm<78>(x)));
    else if constexpr (LM == 12) return dppm<320>(dppm<27>(x));
    else if constexpr (LM == 15) return dppm<320>(x);
    else if constexpr (LM == 16) return x16(x, lane);
    else if constexpr (LM == 32) return x32(x, lane);
    else if constexpr (LM == 48) return x32(x16(x, lane), lane);
    else                         return xli<LM & 48>(xli<LM & 15>(x, lane), lane);
}

template<int LM>
__device__ __forceinline__ v2f xlane(v2f v, int lane) {
    return (v2f){ i2f(xli<LM>(f2i(v.x), lane)), i2f(xli<LM>(f2i(v.y), lane)) };
}

// Generalized single-qubit gate under GF(2) index transform (masks verified
// R2-R8). Scalar v_fma_f32 math; slot parity SP compile-time.
template<int MASK, int RMASK>
__device__ __forceinline__ void apply_gate(v2f (&a)[16], float4 r0, float4 r1,
                                           float cq, float sq, int lane)
{
    constexpr int LM = (MASK >> 4) & 63;
    constexpr int JM = MASK & 15;
    constexpr int RH = (RMASK >> 4) & 63;
    constexpr int RL = RMASK & 15;

    // fuse Rot * RY(c,s)
    const float g00r = fmaf(r0.x, cq,  r0.z * sq), g00i = fmaf(r0.y, cq,  r0.w * sq);
    const float g01r = fmaf(r0.z, cq, -r0.x * sq), g01i = fmaf(r0.w, cq, -r0.y * sq);
    const float g10r = fmaf(r1.x, cq,  r1.z * sq), g10i = fmaf(r1.y, cq,  r1.w * sq);
    const float g11r = fmaf(r1.z, cq, -r1.x * sq), g11i = fmaf(r1.w, cq, -r1.y * sq);

    const bool lp = (RH != 0) && (__popc(lane & RH) & 1);
    const float A0r = lp ? g11r : g00r, A0i = lp ? g11i : g00i;
    const float B0r = lp ? g10r : g01r, B0i = lp ? g10i : g01i;
    const float A1r = lp ? g00r : g11r, A1i = lp ? g00i : g11i;
    const float B1r = lp ? g01r : g10r, B1i = lp ? g01i : g10i;

    // phase 1: all partner values (VALU cross-lane, no DS pipe)
    v2f o[16];
    #pragma unroll
    for (int j = 0; j < 16; ++j) o[j] = xlane<LM>(a[j ^ JM], lane);

    // phase 2: 8 scalar FMAs per amp; new = A*a + B*o (complex)
#define QNN_F(J) { constexpr int SP_ = __builtin_popcount((J) & RL) & 1;      \
    const float Ar = SP_ ? A1r : A0r, Ai = SP_ ? A1i : A0i;                   \
    const float Br = SP_ ? B1r : B0r, Bi = SP_ ? B1i : B0i;                   \
    const float ar = a[J].x, ai = a[J].y, pr = o[J].x, pi = o[J].y;           \
    float re = ar * Ar;       re = fmaf(-Ai, ai, re);                         \
    re = fmaf(Br, pr, re);    re = fmaf(-Bi, pi, re);                         \
    float im = ai * Ar;       im = fmaf(Ai, ar, im);                          \
    im = fmaf(Br, pi, im);    im = fmaf(Bi, pr, im);                          \
    a[J] = (v2f){re, im}; }
    QNN_F(0) QNN_F(1) QNN_F(2) QNN_F(3) QNN_F(4) QNN_F(5) QNN_F(6) QNN_F(7)
    QNN_F(8) QNN_F(9) QNN_F(10) QNN_F(11) QNN_F(12) QNN_F(13) QNN_F(14) QNN_F(15)
#undef QNN_F
}

__global__ __launch_bounds__(256, 4)
void qnn_kernel(const float* __restrict__ x, const float* __restrict__ w,
                float* __restrict__ out)
{
    __shared__ float4 rotL[NL * NQ][2];   // (R00,R01) | (R10,R11)

    const int t    = threadIdx.x;
    const int lane = t & 63;
    const int b    = blockIdx.x * 4 + (t >> 6);   // one wave per batch element

    if (t < NL * NQ) {
        const float* wp = w + t * 3;
        float phi = wp[0], th = wp[1], om = wp[2];
        float ct = cosf(th * 0.5f), st = sinf(th * 0.5f);
        float ap = (phi + om) * 0.5f, am = (phi - om) * 0.5f;
        float cap = cosf(ap), sap = sinf(ap);
        float cam = cosf(am), sam = sinf(am);
        rotL[t][0] = make_float4(cap * ct, -sap * ct, -cam * st, -sam * st);
        rotL[t][1] = make_float4(cam * st, -sam * st,  cap * ct,  sap * ct);
    }
    __syncthreads();

    // ---- per-batch RY cos/sin (wave-uniform -> SGPR via readfirstlane) ----
    const float* xb = x + (size_t)__builtin_amdgcn_readfirstlane(b * NQ);
    float c_[NQ], s_[NQ];
    #pragma unroll
    for (int q = 0; q < NQ; ++q) {
        float xv = xb[q] * 0.5f;
        c_[q] = i2f(__builtin_amdgcn_readfirstlane(f2i(__cosf(xv))));
        s_[q] = i2f(__builtin_amdgcn_readfirstlane(f2i(__sinf(xv))));
    }

    // ---- layer 1 analytic: product state amp[p] = prod_q col0(G_q)[bit_q(p)] ----
    v2f c0[4], c1[4];
    v2f Ln = {1.f, 0.f};
    #pragma unroll
    for (int q = 0; q < NQ; ++q) {
        float4 r0 = rotL[q][0], r1 = rotL[q][1];
        float cq = c_[q], sq = s_[q];
        v2f g0 = { fmaf(r0.x, cq, r0.z * sq), fmaf(r0.y, cq, r0.w * sq) };
        v2f g1 = { fmaf(r1.x, cq, r1.z * sq), fmaf(r1.y, cq, r1.w * sq) };
        if (q < 4) { c0[q] = g0; c1[q] = g1; }
        else {
            v2f gg = ((lane >> (q - 4)) & 1) ? g1 : g0;
            Ln = (q == 4) ? gg : cmul(Ln, gg);
        }
    }
    v2f S01[4], SH[4];
    #pragma unroll
    for (int j = 0; j < 4; ++j)
        S01[j] = cmul((j & 1) ? c1[0] : c0[0], (j & 2) ? c1[1] : c0[1]);
    #pragma unroll
    for (int h = 0; h < 4; ++h)
        SH[h] = cmul(cmul((h & 1) ? c1[2] : c0[2], (h & 2) ? c1[3] : c0[3]), Ln);
    v2f a[16];
    #pragma unroll
    for (int j = 0; j < 16; ++j)
        a[j] = cmul(S01[j & 3], SH[j >> 2]);

    // ---- layers 2..3 (masks + parities verified in R2/R3/R5/R8) ----
#define GATE(IDX, Q, MASK, RMASK) \
    apply_gate<MASK, RMASK>(a, rotL[IDX][0], rotL[IDX][1], c_[Q], s_[Q], lane);
    GATE(10, 0, 0x003, 0x3FE)  GATE(11, 1, 0x006, 0x003)
    GATE(12, 2, 0x00C, 0x007)  GATE(13, 3, 0x018, 0x00F)
    GATE(14, 4, 0x030, 0x01F)  GATE(15, 5, 0x060, 0x03F)
    GATE(16, 6, 0x0C0, 0x07F)  GATE(17, 7, 0x180, 0x0FF)
    GATE(18, 8, 0x300, 0x1FF)  GATE(19, 9, 0x203, 0x3FF)
    GATE(20, 0, 0x005, 0x2AB)  GATE(21, 1, 0x00A, 0x3FD)
    GATE(22, 2, 0x014, 0x3FA)  GATE(23, 3, 0x028, 0x3F5)
    GATE(24, 4, 0x050, 0x3EA)  GATE(25, 5, 0x0A0, 0x3D5)
    GATE(26, 6, 0x140, 0x3AA)  GATE(27, 7, 0x280, 0x355)
    GATE(28, 8, 0x103, 0x2AA)  GATE(29, 9, 0x206, 0x155)
#undef GATE

    // ---- probabilities + 4-bit Walsh-Hadamard over slots ----
    float P[16];
    #pragma unroll
    for (int j = 0; j < 16; ++j)
        P[j] = fmaf(a[j].x, a[j].x, a[j].y * a[j].y);
    #pragma unroll
    for (int bit = 0; bit < 4; ++bit) {
        #pragma unroll
        for (int j = 0; j < 16; ++j)
            if (!(j & (1 << bit))) {
                int k = j | (1 << bit);
                float u = P[j], v = P[k];
                P[j] = u + v;
                P[k] = u - v;
            }
    }

    float vout = 0.f;
#define MEAS(Q, RM)                                                           \
    { constexpr int RH_ = ((RM) >> 4) & 63;                                   \
      constexpr int RL_ = (RM) & 15;                                          \
      float v = P[RL_];                                                       \
      if (__popc(lane & RH_) & 1) v = -v;                                     \
      v += i2f(dppm<177>(f2i(v)));                 /* xor1  */                \
      v += i2f(dppm<78>(f2i(v)));                  /* xor2  */                \
      v += i2f(dppm<321>(dppm<27>(f2i(v))));       /* xor4 = 7^3 */           \
      v += i2f(dppm<320>(dppm<321>(f2i(v))));      /* xor8 = 15^7 */          \
      v += i2f(x16(f2i(v), lane));                 /* xor16 */                \
      v += i2f(x32(f2i(v), lane));                 /* xor32 */                \
      if (lane == (Q)) vout = v; }
    MEAS(0, 0x0CD) MEAS(1, 0x156) MEAS(2, 0x2AC) MEAS(3, 0x159)
    MEAS(4, 0x2B3) MEAS(5, 0x166) MEAS(6, 0x2CC) MEAS(7, 0x199)
    MEAS(8, 0x333) MEAS(9, 0x266)
#undef MEAS

    if (lane < NQ) out[b * NQ + lane] = vout;
}

extern "C" void kernel_launch(void* const* d_in, const int* in_sizes, int n_in,
                              void* d_out, int out_size, void* d_ws, size_t ws_size,
                              hipStream_t stream) {
    const float* x = (const float*)d_in[0];   // (4096, 10) f32
    const float* w = (const float*)d_in[1];   // (3, 10, 3) f32
    float* out = (float*)d_out;               // (4096, 10) f32
    const int B = in_sizes[0] / NQ;           // 4096
    qnn_kernel<<<B / 4, 256, 0, stream>>>(x, w, out);
}

// Round 10
// 83.119 us; speedup vs baseline: 1.0787x; 1.0787x over previous
//
#include <hip/hip_runtime.h>

#define NQ 10
#define NL 3

typedef float    v2f __attribute__((ext_vector_type(2)));
typedef unsigned u2v __attribute__((ext_vector_type(2)));

#if defined(__has_builtin)
#if __has_builtin(__builtin_amdgcn_permlane16_swap) && __has_builtin(__builtin_amdgcn_permlane32_swap)
#define QNN_PERML 1
#endif
#endif

__device__ __forceinline__ int   f2i(float v) { union { float f; int i; } u; u.f = v; return u.i; }
__device__ __forceinline__ float i2f(int v)   { union { int i; float f; } u; u.i = v; return u.f; }

__device__ __forceinline__ v2f cmul(v2f a, v2f b) {
    return (v2f){ fmaf(a.x, b.x, -a.y * b.y), fmaf(a.x, b.y, a.y * b.x) };
}

template<int C> __device__ __forceinline__ int dppm(int v) {
    return __builtin_amdgcn_mov_dpp(v, C, 0xF, 0xF, false);
}

// ---- VALU-pipe xor-16/32 via permlane swaps (semantics verified R9) ----
__device__ __forceinline__ int x16(int v, int lane) {
#ifdef QNN_PERML
    u2v r = __builtin_amdgcn_permlane16_swap(v, v, false, false);
    return (lane & 16) ? (int)r.x : (int)r.y;
#else
    return __builtin_amdgcn_ds_swizzle(v, (16 << 10) | 0x1F);
#endif
}
__device__ __forceinline__ int x32(int v, int lane) {
#ifdef QNN_PERML
    u2v r = __builtin_amdgcn_permlane32_swap(v, v, false, false);
    return (lane & 32) ? (int)r.x : (int)r.y;
#else
    return __builtin_amdgcn_ds_bpermute((lane ^ 32) << 2, v);
#endif
}

// VALU-pipe xor exchange by mask (DPP atoms compose by XOR; verified R9)
template<int LM>
__device__ __forceinline__ int xvi(int x, int lane) {
    if constexpr (LM == 0)       return x;
    else if constexpr (LM == 1)  return dppm<177>(x);
    else if constexpr (LM == 2)  return dppm<78>(x);
    else if constexpr (LM == 3)  return dppm<27>(x);
    else if constexpr (LM == 4)  return dppm<321>(dppm<27>(x));
    else if constexpr (LM == 5)  return dppm<321>(dppm<78>(x));
    else if constexpr (LM == 6)  return dppm<321>(dppm<177>(x));
    else if constexpr (LM == 7)  return dppm<321>(x);
    else if constexpr (LM == 8)  return dppm<320>(dppm<321>(x));
    else if constexpr (LM == 10) return dppm<320>(dppm<321>(dppm<78>(x)));
    else if constexpr (LM == 12) return dppm<320>(dppm<27>(x));
    else if constexpr (LM == 15) return dppm<320>(x);
    else if constexpr (LM == 16) return x16(x, lane);
    else if constexpr (LM == 32) return x32(x, lane);
    else if constexpr (LM == 48) return x32(x16(x, lane), lane);
    else                         return xvi<LM & 48>(xvi<LM & 15>(x, lane), lane);
}
template<int LM>
__device__ __forceinline__ v2f xv(v2f v, int lane) {
    return (v2f){ i2f(xvi<LM>(f2i(v.x), lane)), i2f(xvi<LM>(f2i(v.y), lane)) };
}

// DS-pipe xor exchange (verified R8)
template<int LM>
__device__ __forceinline__ v2f xds(v2f v, int baddr) {
    int x = f2i(v.x), y = f2i(v.y);
    if constexpr (LM < 32) {
        constexpr int off = (LM << 10) | 0x1F;   // BitMode xor
        x = __builtin_amdgcn_ds_swizzle(x, off);
        y = __builtin_amdgcn_ds_swizzle(y, off);
    } else {
        x = __builtin_amdgcn_ds_bpermute(baddr, x);
        y = __builtin_amdgcn_ds_bpermute(baddr, y);
    }
    return (v2f){ i2f(x), i2f(y) };
}

// Generalized single-qubit gate under GF(2) index transform (masks verified
// R2-R9). Exchange routed to BOTH pipes: slots 0-7 via DS, slots 8-15 via
// VALU, so the CU's DS and VALU pipes run concurrently instead of ping-pong.
template<int MASK, int RMASK>
__device__ __forceinline__ void apply_gate(v2f (&a)[16], float4 r0, float4 r1,
                                           float cq, float sq, int lane)
{
    constexpr int LM = (MASK >> 4) & 63;
    constexpr int JM = MASK & 15;
    constexpr int RH = (RMASK >> 4) & 63;
    constexpr int RL = RMASK & 15;

    // fuse Rot * RY(c,s)
    const float g00r = fmaf(r0.x, cq,  r0.z * sq), g00i = fmaf(r0.y, cq,  r0.w * sq);
    const float g01r = fmaf(r0.z, cq, -r0.x * sq), g01i = fmaf(r0.w, cq, -r0.y * sq);
    const float g10r = fmaf(r1.x, cq,  r1.z * sq), g10i = fmaf(r1.y, cq,  r1.w * sq);
    const float g11r = fmaf(r1.z, cq, -r1.x * sq), g11i = fmaf(r1.w, cq, -r1.y * sq);

    const bool lp = (RH != 0) && (__popc(lane & RH) & 1);
    const float A0r = lp ? g11r : g00r, A0i = lp ? g11i : g00i;
    const float B0r = lp ? g10r : g01r, B0i = lp ? g10i : g01i;
    const float A1r = lp ? g00r : g11r, A1i = lp ? g00i : g11i;
    const float B1r = lp ? g01r : g10r, B1i = lp ? g01i : g10i;

    // phase 1: partner values, dual-pipe routed
    v2f o[16];
    if constexpr (LM == 0) {
        #pragma unroll
        for (int j = 0; j < 16; ++j) o[j] = a[j ^ JM];
    } else if constexpr (LM <= 3) {
        #pragma unroll
        for (int j = 0; j < 16; ++j) o[j] = xv<LM>(a[j ^ JM], lane);
    } else {
        const int baddr = ((lane ^ LM) << 2);
        #pragma unroll
        for (int j = 0; j < 8; ++j)  o[j] = xds<LM>(a[j ^ JM], baddr);  // DS pipe
        #pragma unroll
        for (int j = 8; j < 16; ++j) o[j] = xv<LM>(a[j ^ JM], lane);    // VALU pipe
    }

    // phase 2: 8 scalar FMAs per amp; VALU-half slots first so their math
    // overlaps the DS-half's lgkmcnt latency.
#define QNN_F(J) { constexpr int SP_ = __builtin_popcount((J) & RL) & 1;      \
    const float Ar = SP_ ? A1r : A0r, Ai = SP_ ? A1i : A0i;                   \
    const float Br = SP_ ? B1r : B0r, Bi = SP_ ? B1i : B0i;                   \
    const float ar = a[J].x, ai = a[J].y, pr = o[J].x, pi = o[J].y;           \
    float re = ar * Ar;       re = fmaf(-Ai, ai, re);                         \
    re = fmaf(Br, pr, re);    re = fmaf(-Bi, pi, re);                         \
    float im = ai * Ar;       im = fmaf(Ai, ar, im);                          \
    im = fmaf(Br, pi, im);    im = fmaf(Bi, pr, im);                          \
    a[J] = (v2f){re, im}; }
    QNN_F(8) QNN_F(9) QNN_F(10) QNN_F(11) QNN_F(12) QNN_F(13) QNN_F(14) QNN_F(15)
    QNN_F(0) QNN_F(1) QNN_F(2) QNN_F(3) QNN_F(4) QNN_F(5) QNN_F(6) QNN_F(7)
#undef QNN_F
}

__global__ __launch_bounds__(256, 4)
void qnn_kernel(const float* __restrict__ x, const float* __restrict__ w,
                float* __restrict__ out)
{
    __shared__ float4 rotL[NL * NQ][2];   // (R00,R01) | (R10,R11)

    const int t    = threadIdx.x;
    const int lane = t & 63;
    const int b    = blockIdx.x * 4 + (t >> 6);   // one wave per batch element

    if (t < NL * NQ) {
        const float* wp = w + t * 3;
        float phi = wp[0], th = wp[1], om = wp[2];
        float ct = cosf(th * 0.5f), st = sinf(th * 0.5f);
        float ap = (phi + om) * 0.5f, am = (phi - om) * 0.5f;
        float cap = cosf(ap), sap = sinf(ap);
        float cam = cosf(am), sam = sinf(am);
        rotL[t][0] = make_float4(cap * ct, -sap * ct, -cam * st, -sam * st);
        rotL[t][1] = make_float4(cam * st, -sam * st,  cap * ct,  sap * ct);
    }
    __syncthreads();

    // ---- per-batch RY cos/sin (wave-uniform -> SGPR via readfirstlane) ----
    const float* xb = x + (size_t)__builtin_amdgcn_readfirstlane(b * NQ);
    float c_[NQ], s_[NQ];
    #pragma unroll
    for (int q = 0; q < NQ; ++q) {
        float xv_ = xb[q] * 0.5f;
        c_[q] = i2f(__builtin_amdgcn_readfirstlane(f2i(__cosf(xv_))));
        s_[q] = i2f(__builtin_amdgcn_readfirstlane(f2i(__sinf(xv_))));
    }

    // ---- layer 1 analytic: product state amp[p] = prod_q col0(G_q)[bit_q(p)] ----
    v2f c0[4], c1[4];
    v2f Ln = {1.f, 0.f};
    #pragma unroll
    for (int q = 0; q < NQ; ++q) {
        float4 r0 = rotL[q][0], r1 = rotL[q][1];
        float cq = c_[q], sq = s_[q];
        v2f g0 = { fmaf(r0.x, cq, r0.z * sq), fmaf(r0.y, cq, r0.w * sq) };
        v2f g1 = { fmaf(r1.x, cq, r1.z * sq), fmaf(r1.y, cq, r1.w * sq) };
        if (q < 4) { c0[q] = g0; c1[q] = g1; }
        else {
            v2f gg = ((lane >> (q - 4)) & 1) ? g1 : g0;
            Ln = (q == 4) ? gg : cmul(Ln, gg);
        }
    }
    v2f S01[4], SH[4];
    #pragma unroll
    for (int j = 0; j < 4; ++j)
        S01[j] = cmul((j & 1) ? c1[0] : c0[0], (j & 2) ? c1[1] : c0[1]);
    #pragma unroll
    for (int h = 0; h < 4; ++h)
        SH[h] = cmul(cmul((h & 1) ? c1[2] : c0[2], (h & 2) ? c1[3] : c0[3]), Ln);
    v2f a[16];
    #pragma unroll
    for (int j = 0; j < 16; ++j)
        a[j] = cmul(S01[j & 3], SH[j >> 2]);

    // ---- layers 2..3 (masks + parities verified R2-R9) ----
#define GATE(IDX, Q, MASK, RMASK) \
    apply_gate<MASK, RMASK>(a, rotL[IDX][0], rotL[IDX][1], c_[Q], s_[Q], lane);
    GATE(10, 0, 0x003, 0x3FE)  GATE(11, 1, 0x006, 0x003)
    GATE(12, 2, 0x00C, 0x007)  GATE(13, 3, 0x018, 0x00F)
    GATE(14, 4, 0x030, 0x01F)  GATE(15, 5, 0x060, 0x03F)
    GATE(16, 6, 0x0C0, 0x07F)  GATE(17, 7, 0x180, 0x0FF)
    GATE(18, 8, 0x300, 0x1FF)  GATE(19, 9, 0x203, 0x3FF)
    GATE(20, 0, 0x005, 0x2AB)  GATE(21, 1, 0x00A, 0x3FD)
    GATE(22, 2, 0x014, 0x3FA)  GATE(23, 3, 0x028, 0x3F5)
    GATE(24, 4, 0x050, 0x3EA)  GATE(25, 5, 0x0A0, 0x3D5)
    GATE(26, 6, 0x140, 0x3AA)  GATE(27, 7, 0x280, 0x355)
    GATE(28, 8, 0x103, 0x2AA)  GATE(29, 9, 0x206, 0x155)
#undef GATE

    // ---- probabilities + 4-bit Walsh-Hadamard over slots ----
    float P[16];
    #pragma unroll
    for (int j = 0; j < 16; ++j)
        P[j] = fmaf(a[j].x, a[j].x, a[j].y * a[j].y);
    #pragma unroll
    for (int bit = 0; bit < 4; ++bit) {
        #pragma unroll
        for (int j = 0; j < 16; ++j)
            if (!(j & (1 << bit))) {
                int k = j | (1 << bit);
                float u = P[j], v = P[k];
                P[j] = u + v;
                P[k] = u - v;
            }
    }

    const int bp32 = ((lane ^ 32) << 2);
    float vout = 0.f;
#define MEAS(Q, RM)                                                           \
    { constexpr int RH_ = ((RM) >> 4) & 63;                                   \
      constexpr int RL_ = (RM) & 15;                                          \
      float v = P[RL_];                                                       \
      if (__popc(lane & RH_) & 1) v = -v;                                     \
      v += i2f(dppm<177>(f2i(v)));                 /* xor1  */                \
      v += i2f(dppm<78>(f2i(v)));                  /* xor2  */                \
      v += i2f(dppm<321>(dppm<27>(f2i(v))));       /* xor4 = 7^3 */           \
      v += i2f(dppm<320>(dppm<321>(f2i(v))));      /* xor8 = 15^7 */          \
      v += i2f(__builtin_amdgcn_ds_swizzle(f2i(v), (16 << 10) | 0x1F));       \
      v += i2f(__builtin_amdgcn_ds_bpermute(bp32, f2i(v)));                   \
      if (lane == (Q)) vout = v; }
    MEAS(0, 0x0CD) MEAS(1, 0x156) MEAS(2, 0x2AC) MEAS(3, 0x159)
    MEAS(4, 0x2B3) MEAS(5, 0x166) MEAS(6, 0x2CC) MEAS(7, 0x199)
    MEAS(8, 0x333) MEAS(9, 0x266)
#undef MEAS

    if (lane < NQ) out[b * NQ + lane] = vout;
}

extern "C" void kernel_launch(void* const* d_in, const int* in_sizes, int n_in,
                              void* d_out, int out_size, void* d_ws, size_t ws_size,
                              hipStream_t stream) {
    const float* x = (const float*)d_in[0];   // (4096, 10) f32
    const float* w = (const float*)d_in[1];   // (3, 10, 3) f32
    float* out = (float*)d_out;               // (4096, 10) f32
    const int B = in_sizes[0] / NQ;           // 4096
    qnn_kernel<<<B / 4, 256, 0, stream>>>(x, w, out);
}

// Round 11
// 80.914 us; speedup vs baseline: 1.1081x; 1.0273x over previous
//
#include <hip/hip_runtime.h>

#define NQ 10
#define NL 3

typedef float v2f __attribute__((ext_vector_type(2)));

__device__ __forceinline__ int   f2i(float v) { union { float f; int i; } u; u.f = v; return u.i; }
__device__ __forceinline__ float i2f(int v)   { union { int i; float f; } u; u.i = v; return u.f; }

__device__ __forceinline__ v2f cmul(v2f a, v2f b) {
    return (v2f){ fmaf(a.x, b.x, -a.y * b.y), fmaf(a.x, b.y, a.y * b.x) };
}

template<int C> __device__ __forceinline__ int dppm(int v) {
    return __builtin_amdgcn_mov_dpp(v, C, 0xF, 0xF, false);
}

// ---- lane exchange by xor mask LM. Single-DPP for LM 1,2,3; DS pipe for the
// rest (swizzle <32, bpermute >=32). (R8-verified routing.) ----
template<int LM>
__device__ __forceinline__ v2f xlane(v2f v, int baddr) {
    if constexpr (LM == 0) return v;
    int x = f2i(v.x), y = f2i(v.y);
    if constexpr (LM == 1)       { x = dppm<177>(x); y = dppm<177>(y); }
    else if constexpr (LM == 2)  { x = dppm<78>(x);  y = dppm<78>(y); }
    else if constexpr (LM == 3)  { x = dppm<27>(x);  y = dppm<27>(y); }
    else if constexpr (LM < 32) {
        constexpr int off = (LM << 10) | 0x1F;   // BitMode xor
        x = __builtin_amdgcn_ds_swizzle(x, off);
        y = __builtin_amdgcn_ds_swizzle(y, off);
    } else {
        x = __builtin_amdgcn_ds_bpermute(baddr, x);
        y = __builtin_amdgcn_ds_bpermute(baddr, y);
    }
    return (v2f){ i2f(x), i2f(y) };
}

// Generalized single-qubit gate under GF(2) index transform (masks verified
// R2-R10). NEW vs R8: for DS-routed gates, a register scheduling barrier
// (empty asm with +v on all 16 partner values) FORCES the compiler to issue
// all 32 DS ops before the FMA phase. Without it the compiler rematerializes
// each exchange next to its FMA pair (R8 VGPR_Count=36 proves o[] was never
// materialized), paying ~120cyc DS latency ~16x per gate instead of ~1x.
template<int MASK, int RMASK>
__device__ __forceinline__ void apply_gate(v2f (&a)[16], float4 r0, float4 r1,
                                           float cq, float sq, int lane)
{
    constexpr int LM = (MASK >> 4) & 63;
    constexpr int JM = MASK & 15;
    constexpr int RH = (RMASK >> 4) & 63;
    constexpr int RL = RMASK & 15;

    // phase 0: issue ALL partner exchanges (DS ops pipeline back-to-back)
    const int baddr = ((lane ^ LM) << 2);
    v2f o[16];
    #pragma unroll
    for (int j = 0; j < 16; ++j) o[j] = xlane<LM>(a[j ^ JM], baddr);

    // phase 1: build coefficients (~30 VALU ops fill the DS latency window)
    const float g00r = fmaf(r0.x, cq,  r0.z * sq), g00i = fmaf(r0.y, cq,  r0.w * sq);
    const float g01r = fmaf(r0.z, cq, -r0.x * sq), g01i = fmaf(r0.w, cq, -r0.y * sq);
    const float g10r = fmaf(r1.x, cq,  r1.z * sq), g10i = fmaf(r1.y, cq,  r1.w * sq);
    const float g11r = fmaf(r1.z, cq, -r1.x * sq), g11i = fmaf(r1.w, cq, -r1.y * sq);

    const bool lp = (RH != 0) && (__popc(lane & RH) & 1);
    const float A0r = lp ? g11r : g00r, A0i = lp ? g11i : g00i;
    const float B0r = lp ? g10r : g01r, B0i = lp ? g10i : g01i;
    const float A1r = lp ? g00r : g11r, A1i = lp ? g00i : g11i;
    const float B1r = lp ? g01r : g10r, B1i = lp ? g01i : g10i;

    // scheduling barrier: pin the batch (DS gates only)
    if constexpr (LM >= 4) {
        asm volatile("" : "+v"(o[0]),  "+v"(o[1]),  "+v"(o[2]),  "+v"(o[3]),
                          "+v"(o[4]),  "+v"(o[5]),  "+v"(o[6]),  "+v"(o[7]),
                          "+v"(o[8]),  "+v"(o[9]),  "+v"(o[10]), "+v"(o[11]),
                          "+v"(o[12]), "+v"(o[13]), "+v"(o[14]), "+v"(o[15]));
    }

    // phase 2: 8 scalar FMAs per amp; new = A*a + B*o (complex)
#define QNN_F(J) { constexpr int SP_ = __builtin_popcount((J) & RL) & 1;      \
    const float Ar = SP_ ? A1r : A0r, Ai = SP_ ? A1i : A0i;                   \
    const float Br = SP_ ? B1r : B0r, Bi = SP_ ? B1i : B0i;                   \
    const float ar = a[J].x, ai = a[J].y, pr = o[J].x, pi = o[J].y;           \
    float re = ar * Ar;       re = fmaf(-Ai, ai, re);                         \
    re = fmaf(Br, pr, re);    re = fmaf(-Bi, pi, re);                         \
    float im = ai * Ar;       im = fmaf(Ai, ar, im);                          \
    im = fmaf(Br, pi, im);    im = fmaf(Bi, pr, im);                          \
    a[J] = (v2f){re, im}; }
    QNN_F(0) QNN_F(1) QNN_F(2) QNN_F(3) QNN_F(4) QNN_F(5) QNN_F(6) QNN_F(7)
    QNN_F(8) QNN_F(9) QNN_F(10) QNN_F(11) QNN_F(12) QNN_F(13) QNN_F(14) QNN_F(15)
#undef QNN_F
}

__global__ __launch_bounds__(256, 4)
void qnn_kernel(const float* __restrict__ x, const float* __restrict__ w,
                float* __restrict__ out)
{
    __shared__ float4 rotL[NL * NQ][2];   // (R00,R01) | (R10,R11)

    const int t    = threadIdx.x;
    const int lane = t & 63;
    const int b    = blockIdx.x * 4 + (t >> 6);   // one wave per batch element

    if (t < NL * NQ) {
        const float* wp = w + t * 3;
        float phi = wp[0], th = wp[1], om = wp[2];
        float ct = cosf(th * 0.5f), st = sinf(th * 0.5f);
        float ap = (phi + om) * 0.5f, am = (phi - om) * 0.5f;
        float cap = cosf(ap), sap = sinf(ap);
        float cam = cosf(am), sam = sinf(am);
        rotL[t][0] = make_float4(cap * ct, -sap * ct, -cam * st, -sam * st);
        rotL[t][1] = make_float4(cam * st, -sam * st,  cap * ct,  sap * ct);
    }
    __syncthreads();

    // ---- per-batch RY cos/sin (wave-uniform -> SGPR via readfirstlane) ----
    const float* xb = x + (size_t)__builtin_amdgcn_readfirstlane(b * NQ);
    float c_[NQ], s_[NQ];
    #pragma unroll
    for (int q = 0; q < NQ; ++q) {
        float xv = xb[q] * 0.5f;
        c_[q] = i2f(__builtin_amdgcn_readfirstlane(f2i(__cosf(xv))));
        s_[q] = i2f(__builtin_amdgcn_readfirstlane(f2i(__sinf(xv))));
    }

    // ---- layer 1 analytic: product state amp[p] = prod_q col0(G_q)[bit_q(p)] ----
    v2f c0[4], c1[4];
    v2f Ln = {1.f, 0.f};
    #pragma unroll
    for (int q = 0; q < NQ; ++q) {
        float4 r0 = rotL[q][0], r1 = rotL[q][1];
        float cq = c_[q], sq = s_[q];
        v2f g0 = { fmaf(r0.x, cq, r0.z * sq), fmaf(r0.y, cq, r0.w * sq) };
        v2f g1 = { fmaf(r1.x, cq, r1.z * sq), fmaf(r1.y, cq, r1.w * sq) };
        if (q < 4) { c0[q] = g0; c1[q] = g1; }
        else {
            v2f gg = ((lane >> (q - 4)) & 1) ? g1 : g0;
            Ln = (q == 4) ? gg : cmul(Ln, gg);
        }
    }
    v2f S01[4], SH[4];
    #pragma unroll
    for (int j = 0; j < 4; ++j)
        S01[j] = cmul((j & 1) ? c1[0] : c0[0], (j & 2) ? c1[1] : c0[1]);
    #pragma unroll
    for (int h = 0; h < 4; ++h)
        SH[h] = cmul(cmul((h & 1) ? c1[2] : c0[2], (h & 2) ? c1[3] : c0[3]), Ln);
    v2f a[16];
    #pragma unroll
    for (int j = 0; j < 16; ++j)
        a[j] = cmul(S01[j & 3], SH[j >> 2]);

    // ---- layers 2..3 (masks + parities verified R2-R10) ----
#define GATE(IDX, Q, MASK, RMASK) \
    apply_gate<MASK, RMASK>(a, rotL[IDX][0], rotL[IDX][1], c_[Q], s_[Q], lane);
    GATE(10, 0, 0x003, 0x3FE)  GATE(11, 1, 0x006, 0x003)
    GATE(12, 2, 0x00C, 0x007)  GATE(13, 3, 0x018, 0x00F)
    GATE(14, 4, 0x030, 0x01F)  GATE(15, 5, 0x060, 0x03F)
    GATE(16, 6, 0x0C0, 0x07F)  GATE(17, 7, 0x180, 0x0FF)
    GATE(18, 8, 0x300, 0x1FF)  GATE(19, 9, 0x203, 0x3FF)
    GATE(20, 0, 0x005, 0x2AB)  GATE(21, 1, 0x00A, 0x3FD)
    GATE(22, 2, 0x014, 0x3FA)  GATE(23, 3, 0x028, 0x3F5)
    GATE(24, 4, 0x050, 0x3EA)  GATE(25, 5, 0x0A0, 0x3D5)
    GATE(26, 6, 0x140, 0x3AA)  GATE(27, 7, 0x280, 0x355)
    GATE(28, 8, 0x103, 0x2AA)  GATE(29, 9, 0x206, 0x155)
#undef GATE

    // ---- probabilities + 4-bit Walsh-Hadamard over slots ----
    float P[16];
    #pragma unroll
    for (int j = 0; j < 16; ++j)
        P[j] = fmaf(a[j].x, a[j].x, a[j].y * a[j].y);
    #pragma unroll
    for (int bit = 0; bit < 4; ++bit) {
        #pragma unroll
        for (int j = 0; j < 16; ++j)
            if (!(j & (1 << bit))) {
                int k = j | (1 << bit);
                float u = P[j], v = P[k];
                P[j] = u + v;
                P[k] = u - v;
            }
    }

    const int bp32 = ((lane ^ 32) << 2);
    float vout = 0.f;
#define MEAS(Q, RM)                                                           \
    { constexpr int RH_ = ((RM) >> 4) & 63;                                   \
      constexpr int RL_ = (RM) & 15;                                          \
      float v = P[RL_];                                                       \
      if (__popc(lane & RH_) & 1) v = -v;                                     \
      v += i2f(dppm<177>(f2i(v)));                 /* xor1  */                \
      v += i2f(dppm<78>(f2i(v)));                  /* xor2  */                \
      v += i2f(dppm<321>(dppm<27>(f2i(v))));       /* xor4 = 7^3 */           \
      v += i2f(dppm<320>(dppm<321>(f2i(v))));      /* xor8 = 15^7 */          \
      v += i2f(__builtin_amdgcn_ds_swizzle(f2i(v), (16 << 10) | 0x1F));       \
      v += i2f(__builtin_amdgcn_ds_bpermute(bp32, f2i(v)));                   \
      if (lane == (Q)) vout = v; }
    MEAS(0, 0x0CD) MEAS(1, 0x156) MEAS(2, 0x2AC) MEAS(3, 0x159)
    MEAS(4, 0x2B3) MEAS(5, 0x166) MEAS(6, 0x2CC) MEAS(7, 0x199)
    MEAS(8, 0x333) MEAS(9, 0x266)
#undef MEAS

    if (lane < NQ) out[b * NQ + lane] = vout;
}

extern "C" void kernel_launch(void* const* d_in, const int* in_sizes, int n_in,
                              void* d_out, int out_size, void* d_ws, size_t ws_size,
                              hipStream_t stream) {
    const float* x = (const float*)d_in[0];   // (4096, 10) f32
    const float* w = (const float*)d_in[1];   // (3, 10, 3) f32
    float* out = (float*)d_out;               // (4096, 10) f32
    const int B = in_sizes[0] / NQ;           // 4096
    qnn_kernel<<<B / 4, 256, 0, stream>>>(x, w, out);
}

// Round 16
// 77.366 us; speedup vs baseline: 1.1589x; 1.0459x over previous
//
#include <hip/hip_runtime.h>

#define NQ 10
#define NL 3

typedef float v2f __attribute__((ext_vector_type(2)));

__device__ __forceinline__ int   f2i(float v) { union { float f; int i; } u; u.f = v; return u.i; }
__device__ __forceinline__ float i2f(int v)   { union { int i; float f; } u; u.i = v; return u.f; }

__device__ __forceinline__ v2f cmul(v2f a, v2f b) {
    return (v2f){ fmaf(a.x, b.x, -a.y * b.y), fmaf(a.x, b.y, a.y * b.x) };
}

template<int C> __device__ __forceinline__ int dppm(int v) {
    return __builtin_amdgcn_mov_dpp(v, C, 0xF, 0xF, false);
}

// ---- lane exchange by xor mask LM. Single-DPP only for LM 1,2,3 (2-cyc VALU,
// zero latency). Everything else goes to the DS pipe (swizzle <32, bpermute
// >=32) to keep VALU free for the FMA stream. (R8-verified best routing.) ----
template<int LM>
__device__ __forceinline__ v2f xlane(v2f v, int baddr) {
    if constexpr (LM == 0) return v;
    int x = f2i(v.x), y = f2i(v.y);
    if constexpr (LM == 1)       { x = dppm<177>(x); y = dppm<177>(y); }
    else if constexpr (LM == 2)  { x = dppm<78>(x);  y = dppm<78>(y); }
    else if constexpr (LM == 3)  { x = dppm<27>(x);  y = dppm<27>(y); }
    else if constexpr (LM < 32) {
        constexpr int off = (LM << 10) | 0x1F;   // BitMode xor
        x = __builtin_amdgcn_ds_swizzle(x, off);
        y = __builtin_amdgcn_ds_swizzle(y, off);
    } else {
        x = __builtin_amdgcn_ds_bpermute(baddr, x);
        y = __builtin_amdgcn_ds_bpermute(baddr, y);
    }
    return (v2f){ i2f(x), i2f(y) };
}

// Generalized single-qubit gate under GF(2) index transform (masks verified
// R2-R11). Scalar v_fma_f32 math (8 FMA/amp, neg folded into operand
// modifiers); slot parity SP is compile-time so coefficient choice is free.
template<int MASK, int RMASK>
__device__ __forceinline__ void apply_gate(v2f (&a)[16], float4 r0, float4 r1,
                                           float cq, float sq, int lane)
{
    constexpr int LM = (MASK >> 4) & 63;
    constexpr int JM = MASK & 15;
    constexpr int RH = (RMASK >> 4) & 63;
    constexpr int RL = RMASK & 15;

    // fuse Rot * RY(c,s)
    const float g00r = fmaf(r0.x, cq,  r0.z * sq), g00i = fmaf(r0.y, cq,  r0.w * sq);
    const float g01r = fmaf(r0.z, cq, -r0.x * sq), g01i = fmaf(r0.w, cq, -r0.y * sq);
    const float g10r = fmaf(r1.x, cq,  r1.z * sq), g10i = fmaf(r1.y, cq,  r1.w * sq);
    const float g11r = fmaf(r1.z, cq, -r1.x * sq), g11i = fmaf(r1.w, cq, -r1.y * sq);

    const bool lp = (RH != 0) && (__popc(lane & RH) & 1);
    // parity-0 (total parity even) and parity-1 coefficient sets
    const float A0r = lp ? g11r : g00r, A0i = lp ? g11i : g00i;
    const float B0r = lp ? g10r : g01r, B0i = lp ? g10i : g01i;
    const float A1r = lp ? g00r : g11r, A1i = lp ? g00i : g11i;
    const float B1r = lp ? g01r : g10r, B1i = lp ? g01i : g10i;

    const int baddr = ((lane ^ LM) << 2);

    // phase 1: all partner values (independent -> batched DS/DPP issue)
    v2f o[16];
    #pragma unroll
    for (int j = 0; j < 16; ++j) o[j] = xlane<LM>(a[j ^ JM], baddr);

    // phase 2: 8 scalar FMAs per amp; new = A*a + B*o (complex)
#define QNN_F(J) { constexpr int SP_ = __builtin_popcount((J) & RL) & 1;      \
    const float Ar = SP_ ? A1r : A0r, Ai = SP_ ? A1i : A0i;                   \
    const float Br = SP_ ? B1r : B0r, Bi = SP_ ? B1i : B0i;                   \
    const float ar = a[J].x, ai = a[J].y, pr = o[J].x, pi = o[J].y;           \
    float re = ar * Ar;       re = fmaf(-Ai, ai, re);                         \
    re = fmaf(Br, pr, re);    re = fmaf(-Bi, pi, re);                         \
    float im = ai * Ar;       im = fmaf(Ai, ar, im);                          \
    im = fmaf(Br, pi, im);    im = fmaf(Bi, pr, im);                          \
    a[J] = (v2f){re, im}; }
    QNN_F(0) QNN_F(1) QNN_F(2) QNN_F(3) QNN_F(4) QNN_F(5) QNN_F(6) QNN_F(7)
    QNN_F(8) QNN_F(9) QNN_F(10) QNN_F(11) QNN_F(12) QNN_F(13) QNN_F(14) QNN_F(15)
#undef QNN_F
}

__global__ __launch_bounds__(256, 4)
void qnn_kernel(const float* __restrict__ x, const float* __restrict__ w,
                float* __restrict__ out)
{
    __shared__ float4 rotL[NL * NQ][2];   // (R00,R01) | (R10,R11)

    const int t    = threadIdx.x;
    const int lane = t & 63;
    const int b    = blockIdx.x * 4 + (t >> 6);   // one wave per batch element

    if (t < NL * NQ) {
        const float* wp = w + t * 3;
        float phi = wp[0], th = wp[1], om = wp[2];
        float ct = cosf(th * 0.5f), st = sinf(th * 0.5f);
        float ap = (phi + om) * 0.5f, am = (phi - om) * 0.5f;
        float cap = cosf(ap), sap = sinf(ap);
        float cam = cosf(am), sam = sinf(am);
        rotL[t][0] = make_float4(cap * ct, -sap * ct, -cam * st, -sam * st);
        rotL[t][1] = make_float4(cam * st, -sam * st,  cap * ct,  sap * ct);
    }
    __syncthreads();

    // ---- per-batch RY cos/sin (wave-uniform -> SGPR via readfirstlane) ----
    const float* xb = x + (size_t)__builtin_amdgcn_readfirstlane(b * NQ);
    float c_[NQ], s_[NQ];
    #pragma unroll
    for (int q = 0; q < NQ; ++q) {
        float xv = xb[q] * 0.5f;
        c_[q] = i2f(__builtin_amdgcn_readfirstlane(f2i(__cosf(xv))));
        s_[q] = i2f(__builtin_amdgcn_readfirstlane(f2i(__sinf(xv))));
    }

    // ---- layer 1 analytic: product state amp[p] = prod_q col0(G_q)[bit_q(p)] ----
    v2f c0[4], c1[4];
    v2f Ln = {1.f, 0.f};
    #pragma unroll
    for (int q = 0; q < NQ; ++q) {
        float4 r0 = rotL[q][0], r1 = rotL[q][1];
        float cq = c_[q], sq = s_[q];
        v2f g0 = { fmaf(r0.x, cq, r0.z * sq), fmaf(r0.y, cq, r0.w * sq) };
        v2f g1 = { fmaf(r1.x, cq, r1.z * sq), fmaf(r1.y, cq, r1.w * sq) };
        if (q < 4) { c0[q] = g0; c1[q] = g1; }
        else {
            v2f gg = ((lane >> (q - 4)) & 1) ? g1 : g0;
            Ln = (q == 4) ? gg : cmul(Ln, gg);
        }
    }
    v2f S01[4], SH[4];
    #pragma unroll
    for (int j = 0; j < 4; ++j)
        S01[j] = cmul((j & 1) ? c1[0] : c0[0], (j & 2) ? c1[1] : c0[1]);
    #pragma unroll
    for (int h = 0; h < 4; ++h)
        SH[h] = cmul(cmul((h & 1) ? c1[2] : c0[2], (h & 2) ? c1[3] : c0[3]), Ln);
    v2f a[16];
    #pragma unroll
    for (int j = 0; j < 16; ++j)
        a[j] = cmul(S01[j & 3], SH[j >> 2]);

    // ---- layers 2..3 (masks + parities verified in R2/R3/R5/R8) ----
#define GATE(IDX, Q, MASK, RMASK) \
    apply_gate<MASK, RMASK>(a, rotL[IDX][0], rotL[IDX][1], c_[Q], s_[Q], lane);
    GATE(10, 0, 0x003, 0x3FE)  GATE(11, 1, 0x006, 0x003)
    GATE(12, 2, 0x00C, 0x007)  GATE(13, 3, 0x018, 0x00F)
    GATE(14, 4, 0x030, 0x01F)  GATE(15, 5, 0x060, 0x03F)
    GATE(16, 6, 0x0C0, 0x07F)  GATE(17, 7, 0x180, 0x0FF)
    GATE(18, 8, 0x300, 0x1FF)  GATE(19, 9, 0x203, 0x3FF)
    GATE(20, 0, 0x005, 0x2AB)  GATE(21, 1, 0x00A, 0x3FD)
    GATE(22, 2, 0x014, 0x3FA)  GATE(23, 3, 0x028, 0x3F5)
    GATE(24, 4, 0x050, 0x3EA)  GATE(25, 5, 0x0A0, 0x3D5)
    GATE(26, 6, 0x140, 0x3AA)  GATE(27, 7, 0x280, 0x355)
    GATE(28, 8, 0x103, 0x2AA)  GATE(29, 9, 0x206, 0x155)
#undef GATE

    // ---- probabilities + 4-bit Walsh-Hadamard over slots ----
    float P[16];
    #pragma unroll
    for (int j = 0; j < 16; ++j)
        P[j] = fmaf(a[j].x, a[j].x, a[j].y * a[j].y);
    #pragma unroll
    for (int bit = 0; bit < 4; ++bit) {
        #pragma unroll
        for (int j = 0; j < 16; ++j)
            if (!(j & (1 << bit))) {
                int k = j | (1 << bit);
                float u = P[j], v = P[k];
                P[j] = u + v;
                P[k] = u - v;
            }
    }

    const int bp32 = ((lane ^ 32) << 2);
    float vout = 0.f;
#define MEAS(Q, RM)                                                           \
    { constexpr int RH_ = ((RM) >> 4) & 63;                                   \
      constexpr int RL_ = (RM) & 15;                                          \
      float v = P[RL_];                                                       \
      if (__popc(lane & RH_) & 1) v = -v;                                     \
      v += i2f(dppm<177>(f2i(v)));                 /* xor1  */                \
      v += i2f(dppm<78>(f2i(v)));                  /* xor2  */                \
      v += i2f(dppm<321>(dppm<27>(f2i(v))));       /* xor4 = 7^3 */           \
      v += i2f(dppm<320>(dppm<321>(f2i(v))));      /* xor8 = 15^7 */          \
      v += i2f(__builtin_amdgcn_ds_swizzle(f2i(v), (16 << 10) | 0x1F));       \
      v += i2f(__builtin_amdgcn_ds_bpermute(bp32, f2i(v)));                   \
      if (lane == (Q)) vout = v; }
    MEAS(0, 0x0CD) MEAS(1, 0x156) MEAS(2, 0x2AC) MEAS(3, 0x159)
    MEAS(4, 0x2B3) MEAS(5, 0x166) MEAS(6, 0x2CC) MEAS(7, 0x199)
    MEAS(8, 0x333) MEAS(9, 0x266)
#undef MEAS

    if (lane < NQ) out[b * NQ + lane] = vout;
}

extern "C" void kernel_launch(void* const* d_in, const int* in_sizes, int n_in,
                              void* d_out, int out_size, void* d_ws, size_t ws_size,
                              hipStream_t stream) {
    const float* x = (const float*)d_in[0];   // (4096, 10) f32
    const float* w = (const float*)d_in[1];   // (3, 10, 3) f32
    float* out = (float*)d_out;               // (4096, 10) f32
    const int B = in_sizes[0] / NQ;           // 4096
    qnn_kernel<<<B / 4, 256, 0, stream>>>(x, w, out);
}